// Round 11
// baseline (142.466 us; speedup 1.0000x reference)
//
#include <hip/hip_runtime.h>

// Problem constants
#define BATCH 8
#define CCH   384      // channels C == INNER
#define NTOK  1024     // H*W
#define HEADS 6
#define DHEAD 64
// softmax scale 1/8 and log2(e) folded into Q at projection time:
// qout = Q * 0.125 * 1.4426950408889634, attn uses exp2(s) = bare v_exp.
#define QSCALE 0.18033688011112042f

typedef __bf16 bf16x8 __attribute__((ext_vector_type(8)));
typedef float  f32x4  __attribute__((ext_vector_type(4)));
typedef float  f32x16 __attribute__((ext_vector_type(16)));

#define MFMA16(a, b, c) __builtin_amdgcn_mfma_f32_16x16x32_bf16((a), (b), (c), 0, 0, 0)
#define MFMA32(a, b, c) __builtin_amdgcn_mfma_f32_32x32x16_bf16((a), (b), (c), 0, 0, 0)
#define EXP2(x) __builtin_amdgcn_exp2f(x)

// fp32 -> bf16 RNE, raw bits
__device__ __forceinline__ short f2b(float x) {
    unsigned u = __float_as_uint(x);
    u += 0x7fffu + ((u >> 16) & 1u);
    return (short)(u >> 16);
}

// async global->LDS, 16B/lane. LDS dst = wave-uniform base + lane*16.
__device__ __forceinline__ void gld_lds16(const short* gp, short* lp) {
    __builtin_amdgcn_global_load_lds(
        (const __attribute__((address_space(1))) void*)gp,
        (__attribute__((address_space(3))) void*)lp, 16, 0, 0);
}

// ---- 64x64 xor-swizzled tile staging (4 waves) — verified r3/r4 ----
__device__ __forceinline__ void stage_tile(const short* gbase, size_t gstride,
                                           short* lbase, int wv, int lane) {
#pragma unroll
    for (int t = 0; t < 2; ++t) {
        const int row = t * 8 + (lane >> 3);
        const int c   = (lane & 7) ^ (row & 7);
        gld_lds16(gbase + (size_t)(wv * 16 + row) * gstride + c * 8,
                  lbase + (wv * 16 + t * 8) * 64);
    }
}
__device__ __forceinline__ bf16x8 frag_read(const short* lbase, int row, int c) {
    const int pc = c ^ (row & 7);
    return *(const bf16x8*)(lbase + row * 64 + pc * 8);
}

// Split V fragment read: element e of result holds V[row][tok], tok matching
// the NATURAL post-QK P register order: slots (hi, e) <-> j_local =
// [0,1,2,3,8,9,10,11][e] + 4*hi within the 16-token chunk starting at c0*8.
// Two 8B reads: chunk c0 half hi, chunk c0+1 half hi (xor-swizzled rows).
__device__ __forceinline__ bf16x8 vsplit(const short* lbase, int row, int c0, int hi) {
    const int r7 = row & 7;
    const int pc0 = c0 ^ r7, pc1 = (c0 + 1) ^ r7;
    const unsigned* b = (const unsigned*)(lbase + row * 64);
    const int o0 = pc0 * 4 + hi * 2;   // dword offset within the 32-dword row
    const int o1 = pc1 * 4 + hi * 2;
    union { unsigned u[4]; bf16x8 v; } t;
    t.u[0] = b[o0]; t.u[1] = b[o0 + 1];
    t.u[2] = b[o1]; t.u[3] = b[o1 + 1];
    return t.v;
}

// ---------------------------------------------------------------------------
// gemm128 core: C[128x128] = A[128x384] · B[128x384]^T, both k-contig rows,
// stride CCH. SINGLE-buffered phased loop (stage -> bar -> compute -> bar),
// 32 KB LDS -> 3 blocks/CU. Cross-block wave overlap (m114) replaces the
// intra-block double buffer. S layout: A at S[0..8191], B at S[8192..16383].
// ---------------------------------------------------------------------------
__device__ __forceinline__ void gemm128_core(
    const short* __restrict__ Ag, const short* __restrict__ Bg,
    short* S, f32x4 acc[4][4])
{
    const int tid = threadIdx.x, lane = tid & 63;
    const int l15 = tid & 15, quad = (tid >> 4) & 3, wv = tid >> 6;

#pragma unroll
    for (int kc = 0; kc < 6; ++kc) {
        stage_tile(Ag + kc * 64, CCH, S, wv, lane);
        stage_tile(Ag + kc * 64 + 64 * CCH, CCH, S + 4096, wv, lane);
        stage_tile(Bg + kc * 64, CCH, S + 8192, wv, lane);
        stage_tile(Bg + kc * 64 + 64 * CCH, CCH, S + 12288, wv, lane);
        __syncthreads();
        const short* Atile = S + (wv >> 1) * 4096;          // wi tile
        const short* Btile = S + 8192 + (wv & 1) * 4096;    // wj tile
#pragma unroll
        for (int h = 0; h < 2; ++h) {
            bf16x8 a[4], b[4];
#pragma unroll
            for (int s = 0; s < 4; ++s) {
                a[s] = frag_read(Atile, s * 16 + l15, h * 4 + quad);
                b[s] = frag_read(Btile, s * 16 + l15, h * 4 + quad);
            }
#pragma unroll
            for (int si = 0; si < 4; ++si)
#pragma unroll
                for (int sj = 0; sj < 4; ++sj)
                    acc[si][sj] = MFMA16(a[si], b[sj], acc[si][sj]);
        }
        __syncthreads();
    }
}

// Epilogue: repack the 128x128 bf16 C-tile through cbuf (= the 32 KB SMEM,
// free after the K-loop) so global stores are b128.
__device__ __forceinline__ void epilogue_bf16(
    f32x4 acc[4][4], short* cbuf,
    short* __restrict__ out, size_t obase, int ostride)
{
    const int tid = threadIdx.x;
    const int l15 = tid & 15, quad = (tid >> 4) & 3, wv = tid >> 6;
    const int wi = (wv >> 1) * 64, wj = (wv & 1) * 64;
    __syncthreads();
#pragma unroll
    for (int si = 0; si < 4; ++si)
#pragma unroll
        for (int sj = 0; sj < 4; ++sj)
#pragma unroll
            for (int rr = 0; rr < 4; ++rr)
                cbuf[(wi + si * 16 + quad * 4 + rr) * 128 + wj + sj * 16 + l15] =
                    f2b(acc[si][sj][rr]);
    __syncthreads();
#pragma unroll
    for (int pass = 0; pass < 8; ++pass) {
        const int row = pass * 16 + (tid >> 4);     // 0..127
        bf16x8 vchunk = *(const bf16x8*)(cbuf + row * 128 + l15 * 8);
        *(bf16x8*)(out + obase + (size_t)row * ostride + l15 * 8) = vchunk;
    }
}

// ---------------------------------------------------------------------------
// prep: fused transpose+convert (id<1536), weight convert (id<2112),
// amap zero (id>=2112). grid 2120.
// ---------------------------------------------------------------------------
__global__ __launch_bounds__(256) void prep(
    const float* __restrict__ Xq, const float* __restrict__ Xc,
    const float* __restrict__ w0, const float* __restrict__ w1,
    const float* __restrict__ w2, const float* __restrict__ w3,
    short* __restrict__ Xtq, short* __restrict__ Xtc,
    short* __restrict__ o0, short* __restrict__ o1,
    short* __restrict__ o2, short* __restrict__ o3,
    float* __restrict__ amap)
{
    __shared__ float tile[64][65];
    const int id = blockIdx.x, tid = threadIdx.x;
    if (id < 1536) {
        const int zz = id % 16, t = id / 16;
        const int n0 = (t % 16) * 64, c0 = (t / 16) * 64;
        const float* X = (zz < 8) ? Xq : Xc;
        short* Xt      = (zz < 8) ? Xtq : Xtc;
        const int b = zz & 7;
        const int tx = tid & 15, ty = tid >> 4;
#pragma unroll
        for (int rr = 0; rr < 4; ++rr) {
            const int c = rr * 16 + ty;
            float4 v = *(const float4*)&X[((size_t)(b * CCH + c0 + c)) * NTOK + n0 + tx * 4];
            tile[c][tx * 4 + 0] = v.x; tile[c][tx * 4 + 1] = v.y;
            tile[c][tx * 4 + 2] = v.z; tile[c][tx * 4 + 3] = v.w;
        }
        __syncthreads();
        const int n = tid >> 2, cb = (tid & 3) * 16;
        short tmp[16];
#pragma unroll
        for (int cc = 0; cc < 16; ++cc) tmp[cc] = f2b(tile[cb + cc][n]);
        short* dst = &Xt[((size_t)(b * NTOK + n0 + n)) * CCH + c0 + cb];
        *(int4*)dst = *(int4*)&tmp[0];
        *(int4*)(dst + 8) = *(int4*)&tmp[8];
    } else if (id < 2112) {
        const int w = id - 1536;
        const int which = w / 144;
        const int idx = (w % 144) * 256 + tid;
        const float* s = which == 0 ? w0 : which == 1 ? w1 : which == 2 ? w2 : w3;
        short* d       = which == 0 ? o0 : which == 1 ? o1 : which == 2 ? o2 : o3;
        float4 v = ((const float4*)s)[idx];
        short4 o = make_short4(f2b(v.x), f2b(v.y), f2b(v.z), f2b(v.w));
        ((short4*)d)[idx] = o;
    } else {
        const int o = (id - 2112) * 1024 + tid * 4;
        float4 z = {0.f, 0.f, 0.f, 0.f};
        *(float4*)&amap[o] = z;
    }
}

// ---------------------------------------------------------------------------
// Fused QKV projection, 128x128 tiles. 576 blocks: b=id%8 (XCD-local),
// r=id/8: which=r/24 (0:Q,1:K tok-major; 2:V ch-major), tt=r%24.
// Q output pre-scaled by QSCALE. 32 KB LDS -> one residency round.
// ---------------------------------------------------------------------------
__global__ __launch_bounds__(256, 3) void gemm_qkv(
    const short* __restrict__ xtq, const short* __restrict__ xtc,
    const short* __restrict__ wq, const short* __restrict__ wk,
    const short* __restrict__ wvm,
    short* __restrict__ qout, short* __restrict__ kout, short* __restrict__ vout)
{
    __shared__ __align__(16) short SMEM[16384];   // 32 KB: A | B, cbuf in epi
    const int id = blockIdx.x;
    const int b = id & 7, r = id >> 3;
    const int which = r / 24, tt = r % 24;

    const short *Ag, *Bg;
    short* out;
    size_t obase;
    int ostride;
    if (which < 2) {
        const int it = tt / 3, jt = tt % 3;
        const short* x = (which == 0) ? xtq : xtc;
        const short* W = (which == 0) ? wq : wk;
        Ag = x + ((size_t)(b * NTOK + it * 128)) * CCH;
        Bg = W + (size_t)(jt * 128) * CCH;
        out = (which == 0) ? qout : kout;
        obase = ((size_t)(b * NTOK + it * 128)) * CCH + jt * 128;
        ostride = CCH;
    } else {
        const int ct = tt % 3, nt = tt / 3;
        Ag = wvm + (size_t)(ct * 128) * CCH;
        Bg = xtc + ((size_t)(b * NTOK + nt * 128)) * CCH;
        out = vout;
        obase = ((size_t)(b * CCH + ct * 128)) * NTOK + nt * 128;
        ostride = NTOK;
    }

    f32x4 z4 = {0.f, 0.f, 0.f, 0.f};
    f32x4 acc[4][4];
#pragma unroll
    for (int si = 0; si < 4; ++si)
#pragma unroll
        for (int sj = 0; sj < 4; ++sj) acc[si][sj] = z4;

    gemm128_core(Ag, Bg, &SMEM[0], acc);

    if (which == 0) {
#pragma unroll
        for (int si = 0; si < 4; ++si)
#pragma unroll
            for (int sj = 0; sj < 4; ++sj)
#pragma unroll
                for (int rr = 0; rr < 4; ++rr)
                    acc[si][sj][rr] *= QSCALE;
    }
    epilogue_bf16(acc, &SMEM[0], out, obase, ostride);
}

// ---------------------------------------------------------------------------
// Attention O-pass — swapped-QK^T 32x32 MFMA, in-register P (vsplit pairing,
// verified r2), jsub-split compute (r4), counted-vmcnt ring-3 (r8),
// i-blocking (r10: i-tile 128, 512 threads, grid 384 — halves L2 staging
// traffic). Wave w: g = w&3 (i-group, isub=g*32), js = w>>2 (jsub half =
// finalized d-half). NOTE: no ds_write crosses a raw s_barrier in this
// kernel (only global_load_lds, which vmcnt tracks) — the r10 DS-race was
// in tail_k's amap ring, fixed there with lgkmcnt(0).
// ---------------------------------------------------------------------------
__global__ __launch_bounds__(512, 4) void attn(
    const short* __restrict__ qt, const short* __restrict__ kt,
    const short* __restrict__ vc, short* __restrict__ omid,
    float* __restrict__ rws)
{
    __shared__ __align__(16) short KVst[24576];    // K ring-3 (24 KB) | V ring-3 (24 KB)
    __shared__ float denbuf[8][64];                // 2 KB
    __shared__ float rden_sh[4][32];
    float (*obuf)[16][64] = (float (*)[16][64])(&KVst[0]);  // 32 KB alias (post-drain)

    short* const Kst0 = &KVst[0];
    short* const Vst0 = &KVst[12288];

    const int tid = threadIdx.x, lane = tid & 63;
    const int l31 = lane & 31, hi = lane >> 5;
    const int wv = tid >> 6;           // 0..7
    const int g  = wv & 3;             // i-group
    const int isub = g * 32;
    const int js = wv >> 2;            // jsub half = finalized d-half

    const int id = blockIdx.x;         // 384 blocks
    const int b = id & 7, rr_ = id >> 3;           // 0..47
    const int h = rr_ % 6, i0 = (rr_ / 6) * 128;

    const size_t hoff = (size_t)b * NTOK * CCH + h * DHEAD;
    const short* Kg = kt + hoff;                                   // stride CCH
    const short* Vg = vc + ((size_t)(b * CCH + h * DHEAD)) * NTOK; // stride NTOK

    // Q B-frags hoisted: lane holds Q[i = i0+isub+l31, d = m*16 + hi*8 ..+8]
    const short* qp = qt + hoff + (size_t)(i0 + isub + l31) * CCH + hi * 8;
    bf16x8 qf[4];
#pragma unroll
    for (int m = 0; m < 4; ++m) qf[m] = *(const bf16x8*)(qp + m * 16);

    // prologue: js=0 waves stage K tiles 0,1; js=1 stage V tiles 0,1.
    if (js == 0) {
        stage_tile(Kg, CCH, Kst0, g, lane);
        stage_tile(Kg + (size_t)64 * CCH, CCH, Kst0 + 4096, g, lane);
    } else {
        stage_tile(Vg, NTOK, Vst0, g, lane);
        stage_tile(Vg + 64, NTOK, Vst0 + 4096, g, lane);
    }
    asm volatile("s_waitcnt vmcnt(2)" ::: "memory");   // tile0 landed; tile1 in flight
    __builtin_amdgcn_sched_barrier(0);
    __builtin_amdgcn_s_barrier();
    __builtin_amdgcn_sched_barrier(0);

    const f32x16 z16 = {0,0,0,0,0,0,0,0,0,0,0,0,0,0,0,0};
    f32x16 oacc0 = z16, oacc1 = z16;   // d 0..31 / 32..63
    float den = 0.f;

    for (int jt = 0; jt < 16; ++jt) {
        const int cur = jt % 3;
        // stage tile jt+2 into ring slot (jt+2)%3 (last read in phase jt-1)
        if (jt < 14) {
            const int nxt = (jt + 2) % 3;
            if (js == 0)
                stage_tile(Kg + (size_t)(jt + 2) * 64 * CCH, CCH,
                           Kst0 + nxt * 4096, g, lane);
            else
                stage_tile(Vg + (size_t)(jt + 2) * 64, NTOK,
                           Vst0 + nxt * 4096, g, lane);
        }
        // compute this wave's jsub on tile jt
        {
            const short* Kb = Kst0 + cur * 4096;
            const short* Vb = Vst0 + cur * 4096;
            __builtin_amdgcn_s_setprio(1);
            f32x16 s = z16;
#pragma unroll
            for (int m = 0; m < 4; ++m)
                s = MFMA32(frag_read(Kb, js * 32 + l31, 2 * m + hi), qf[m], s);
            bf16x8 pa0, pa1;
#pragma unroll
            for (int e = 0; e < 8; ++e) {
                const float x0 = EXP2(s[e]);
                const float x1 = EXP2(s[8 + e]);
                den += x0 + x1;
                pa0[e] = (__bf16)x0;
                pa1[e] = (__bf16)x1;
            }
            oacc0 = MFMA32(pa0, vsplit(Vb, l31,      js * 4,     hi), oacc0);
            oacc0 = MFMA32(pa1, vsplit(Vb, l31,      js * 4 + 2, hi), oacc0);
            oacc1 = MFMA32(pa0, vsplit(Vb, 32 + l31, js * 4,     hi), oacc1);
            oacc1 = MFMA32(pa1, vsplit(Vb, 32 + l31, js * 4 + 2, hi), oacc1);
            __builtin_amdgcn_s_setprio(0);
        }
        // end of phase: wait ONLY the tile-jt+1 loads (issued a full phase
        // ago); the 2 newest (tile jt+2) stay in flight across the barrier.
        if (jt < 14)
            asm volatile("s_waitcnt vmcnt(2)" ::: "memory");
        else
            asm volatile("s_waitcnt vmcnt(0)" ::: "memory");
        __builtin_amdgcn_sched_barrier(0);
        __builtin_amdgcn_s_barrier();
        __builtin_amdgcn_sched_barrier(0);
    }
    __syncthreads();   // full drain + fence before obuf aliases the K/V ring

    // ---- epilogue: cross-js combine, normalize, store ----
    const int dh = js;                 // this wave finalizes d-half dh
    if (dh == 0) {
#pragma unroll
        for (int g2 = 0; g2 < 16; ++g2) obuf[wv][g2][lane] = oacc1[g2];
    } else {
#pragma unroll
        for (int g2 = 0; g2 < 16; ++g2) obuf[wv][g2][lane] = oacc0[g2];
    }
    denbuf[wv][lane] = den;
    __syncthreads();

    const float dtot = denbuf[g][l31] + denbuf[g][l31 + 32]
                     + denbuf[g + 4][l31] + denbuf[g + 4][l31 + 32];
    const float rden = 1.0f / dtot;
    if (wv < 4 && lane < 32) {
        rden_sh[wv][lane] = rden;
        rws[((b * 6 + h) << 10) + i0 + isub + lane] = rden;
    }
    __syncthreads();

#pragma unroll
    for (int reg = 0; reg < 16; ++reg) {
        const int crw = (reg & 3) + 8 * (reg >> 2) + 4 * hi;     // i-local 0..31
        const float rd = rden_sh[g][crw];
        const float okeep = (dh == 0) ? oacc0[reg] : oacc1[reg];
        const float ov = (okeep + obuf[wv ^ 4][reg][lane]) * rd;
        omid[((size_t)(b * NTOK + i0 + isub + crw)) * CCH + h * DHEAD + dh * 32 + l31] =
            f2b(ov);
    }
}

// ---------------------------------------------------------------------------
// tail_k: o_proj (id<192) + amap (id>=192) merged (verified r7). The 1536
// short amap blocks backfill the CUs o_proj leaves idle.
// amap ring-3 RACE FIX (r10 post-mortem): colbuf3 is written via ds_write
// and read by other waves after a RAW s_barrier — raw s_barrier does NOT
// wait LDS writes (only __syncthreads emits lgkmcnt(0)). The end-of-phase
// waits now include lgkmcnt(0) to drain the colbuf ds_writes before the
// barrier. vmcnt counting is unchanged (r8-verified).
// ---------------------------------------------------------------------------
__global__ __launch_bounds__(256, 3) void tail_k(
    const short* __restrict__ wo, const short* __restrict__ omid,
    const float* __restrict__ bias, float* __restrict__ Y,
    const short* __restrict__ qt, const short* __restrict__ kt,
    const float* __restrict__ rws, float* __restrict__ amap)
{
    __shared__ __align__(16) short SMEM[16384];   // 32 KB
    const int id = blockIdx.x, tid = threadIdx.x;

    if (id < 192) {
        // ---------------- o_proj part (verbatim r6) ----------------
        const int b = id & 7, r = id >> 3;
        const int ct = r % 3, nt = r / 3;

        const short* Ag = wo + (size_t)(ct * 128) * CCH;
        const short* Bg = omid + ((size_t)(b * NTOK + nt * 128)) * CCH;

        f32x4 z4 = {0.f, 0.f, 0.f, 0.f};
        f32x4 acc[4][4];
#pragma unroll
        for (int si = 0; si < 4; ++si)
#pragma unroll
            for (int sj = 0; sj < 4; ++sj) acc[si][sj] = z4;

        gemm128_core(Ag, Bg, &SMEM[0], acc);

        const int l15 = tid & 15, quad = (tid >> 4) & 3, wv = tid >> 6;
        const int wi = (wv >> 1) * 64, wj = (wv & 1) * 64;
#pragma unroll
        for (int si = 0; si < 4; ++si) {
#pragma unroll
            for (int rr = 0; rr < 4; ++rr) {
                const int ch = ct * 128 + wi + si * 16 + quad * 4 + rr;
                const float bv = bias[ch];
#pragma unroll
                for (int sj = 0; sj < 4; ++sj)
                    Y[((size_t)(b * CCH + ch)) * NTOK + nt * 128 + wj + sj * 16 + l15] =
                        acc[si][sj][rr] + bv;
            }
        }
    } else {
        // ------------- amap part (r6 body + r8 T4 ring-3, race-fixed) -----
        short* Kst3 = &SMEM[0];                                    // 3 x 8 KB
        float (*colbuf3)[4][64] = (float (*)[4][64])(&SMEM[12288]); // 3 KB

        const int lane = tid & 63;
        const int l15 = tid & 15, quad = (tid >> 4) & 3, wv = tid >> 6;
        const int aid = id - 192;
        const int b = aid & 7, r = aid >> 3;        // r in 0..191
        const int h = r % 6, q = r / 6;             // q in 0..31
        const int i0 = (q >> 1) * 64;
        const int jt0 = (q & 1) * 8;

        const size_t hoff = (size_t)b * NTOK * CCH + h * DHEAD;
        const short* Kg = kt + hoff;
        const short* qp = qt + hoff + (size_t)(i0 + wv * 16 + l15) * CCH + quad * 8;
        const bf16x8 qa0 = *(const bf16x8*)qp;
        const bf16x8 qa1 = *(const bf16x8*)(qp + 32);

        float rdl[4];
#pragma unroll
        for (int rr = 0; rr < 4; ++rr)
            rdl[rr] = rws[((b * 6 + h) << 10) + i0 + wv * 16 + quad * 4 + rr];

        // prologue: tiles jt0, jt0+1 into slots 0,1 (2+2 gld/thread)
        stage_tile(Kg + (size_t)jt0 * 64 * CCH, CCH, Kst3, wv, lane);
        stage_tile(Kg + (size_t)(jt0 + 1) * 64 * CCH, CCH, Kst3 + 4096, wv, lane);
        asm volatile("s_waitcnt vmcnt(2)" ::: "memory");
        __builtin_amdgcn_sched_barrier(0);
        __builtin_amdgcn_s_barrier();
        __builtin_amdgcn_sched_barrier(0);

        for (int t = 0; t < 8; ++t) {
            const int jt = jt0 + t;
            const int cur = t % 3;
            if (t < 6)
                stage_tile(Kg + (size_t)(jt + 2) * 64 * CCH, CCH,
                           Kst3 + ((t + 2) % 3) * 4096, wv, lane);
            const short* Kb = Kst3 + cur * 4096;
            f32x4 z4 = {0.f, 0.f, 0.f, 0.f};
            f32x4 s[4] = {z4, z4, z4, z4};
#pragma unroll
            for (int ns = 0; ns < 4; ++ns) {
                const int row = ns * 16 + l15;
                bf16x8 k0 = frag_read(Kb, row, quad);
                bf16x8 k1 = frag_read(Kb, row, quad + 4);
                s[ns] = MFMA16(qa0, k0, s[ns]);
                s[ns] = MFMA16(qa1, k1, s[ns]);
            }
#pragma unroll
            for (int ns = 0; ns < 4; ++ns) {
                float cs = EXP2(s[ns][0]) * rdl[0] + EXP2(s[ns][1]) * rdl[1]
                         + EXP2(s[ns][2]) * rdl[2] + EXP2(s[ns][3]) * rdl[3];
                cs += __shfl_xor(cs, 16);
                cs += __shfl_xor(cs, 32);
                if (quad == 0) colbuf3[cur][wv][ns * 16 + l15] = cs;
            }
            // RACE FIX: lgkmcnt(0) drains the colbuf3 ds_writes before the
            // raw barrier (vmcnt covers only the global_load_lds staging).
            if (t < 6)
                asm volatile("s_waitcnt vmcnt(2) lgkmcnt(0)" ::: "memory");
            else
                asm volatile("s_waitcnt vmcnt(0) lgkmcnt(0)" ::: "memory");
            __builtin_amdgcn_sched_barrier(0);
            __builtin_amdgcn_s_barrier();
            __builtin_amdgcn_sched_barrier(0);
            if (tid < 64) {
                const float tsum = colbuf3[cur][0][tid] + colbuf3[cur][1][tid]
                                 + colbuf3[cur][2][tid] + colbuf3[cur][3][tid];
                atomicAdd(amap + (size_t)b * NTOK + jt * 64 + tid,
                          tsum * (1.0f / (HEADS * NTOK)));
            }
        }
    }
}

// ---------------------------------------------------------------------------
extern "C" void kernel_launch(void* const* d_in, const int* in_sizes, int n_in,
                              void* d_out, int out_size, void* d_ws, size_t ws_size,
                              hipStream_t stream)
{
    const float* query   = (const float*)d_in[0];
    const float* context = (const float*)d_in[1];
    const float* Wq      = (const float*)d_in[2];
    const float* Wk      = (const float*)d_in[3];
    const float* Wv      = (const float*)d_in[4];
    const float* Wo      = (const float*)d_in[5];
    const float* bo      = (const float*)d_in[6];

    float* out = (float*)d_out;                          // [8,384,1024] fp32
    const size_t out_elems = (size_t)BATCH * CCH * NTOK;
    float* attn_map = out + out_elems;                   // [8,1024] fp32

    short* ws = (short*)d_ws;
    const size_t XT = (size_t)BATCH * NTOK * CCH;
    const size_t WSZ = (size_t)CCH * CCH;
    short* xtq  = ws;
    short* xtc  = xtq + XT;
    short* wqb  = xtc + XT;
    short* wkb  = wqb + WSZ;
    short* wvb  = wkb + WSZ;
    short* wob  = wvb + WSZ;
    short* qtb  = wob + WSZ;
    short* ktb  = qtb + XT;
    short* vcb  = ktb + XT;
    short* omid = vcb + XT;
    float* rws  = (float*)(omid + XT);                   // [8*6*1024] fp32 rden

    const dim3 blk(256);
    const dim3 blk512(512);

    prep<<<dim3(2120), blk, 0, stream>>>(query, context, Wq, Wk, Wv, Wo,
                                         xtq, xtc, wqb, wkb, wvb, wob, attn_map);

    gemm_qkv<<<dim3(576), blk, 0, stream>>>(xtq, xtc, wqb, wkb, wvb,
                                            qtb, ktb, vcb);

    attn<<<dim3(384), blk512, 0, stream>>>(qtb, ktb, vcb, omid, rws);

    tail_k<<<dim3(1728), blk, 0, stream>>>(wob, omid, bo, out,
                                           qtb, ktb, rws, attn_map);
}

// Round 12
// 139.022 us; speedup vs baseline: 1.0248x; 1.0248x over previous
//
#include <hip/hip_runtime.h>

// Problem constants
#define BATCH 8
#define CCH   384      // channels C == INNER
#define NTOK  1024     // H*W
#define HEADS 6
#define DHEAD 64
// softmax scale 1/8 and log2(e) folded into Q at projection time:
// qout = Q * 0.125 * 1.4426950408889634, attn uses exp2(s) = bare v_exp.
#define QSCALE 0.18033688011112042f

typedef __bf16 bf16x8 __attribute__((ext_vector_type(8)));
typedef float  f32x4  __attribute__((ext_vector_type(4)));
typedef float  f32x16 __attribute__((ext_vector_type(16)));

#define MFMA16(a, b, c) __builtin_amdgcn_mfma_f32_16x16x32_bf16((a), (b), (c), 0, 0, 0)
#define MFMA32(a, b, c) __builtin_amdgcn_mfma_f32_32x32x16_bf16((a), (b), (c), 0, 0, 0)
#define EXP2(x) __builtin_amdgcn_exp2f(x)

// fp32 -> bf16 RNE, raw bits
__device__ __forceinline__ short f2b(float x) {
    unsigned u = __float_as_uint(x);
    u += 0x7fffu + ((u >> 16) & 1u);
    return (short)(u >> 16);
}

// async global->LDS, 16B/lane. LDS dst = wave-uniform base + lane*16.
__device__ __forceinline__ void gld_lds16(const short* gp, short* lp) {
    __builtin_amdgcn_global_load_lds(
        (const __attribute__((address_space(1))) void*)gp,
        (__attribute__((address_space(3))) void*)lp, 16, 0, 0);
}

// ---- 64x64 xor-swizzled tile staging (4 waves) — verified r3/r4 ----
__device__ __forceinline__ void stage_tile(const short* gbase, size_t gstride,
                                           short* lbase, int wv, int lane) {
#pragma unroll
    for (int t = 0; t < 2; ++t) {
        const int row = t * 8 + (lane >> 3);
        const int c   = (lane & 7) ^ (row & 7);
        gld_lds16(gbase + (size_t)(wv * 16 + row) * gstride + c * 8,
                  lbase + (wv * 16 + t * 8) * 64);
    }
}
// same tile, staged by 2 waves (sw = 0/1), 4 gld per thread
__device__ __forceinline__ void stage_tile_2w(const short* gbase, size_t gstride,
                                              short* lbase, int sw, int lane) {
#pragma unroll
    for (int t = 0; t < 4; ++t) {
        const int row = sw * 32 + t * 8 + (lane >> 3);
        const int c   = (lane & 7) ^ (row & 7);
        gld_lds16(gbase + (size_t)row * gstride + c * 8,
                  lbase + (sw * 32 + t * 8) * 64);
    }
}
__device__ __forceinline__ bf16x8 frag_read(const short* lbase, int row, int c) {
    const int pc = c ^ (row & 7);
    return *(const bf16x8*)(lbase + row * 64 + pc * 8);
}

// Split V fragment read: element e of result holds V[row][tok], tok matching
// the NATURAL post-QK P register order: slots (hi, e) <-> j_local =
// [0,1,2,3,8,9,10,11][e] + 4*hi within the 16-token chunk starting at c0*8.
// Two 8B reads: chunk c0 half hi, chunk c0+1 half hi (xor-swizzled rows).
__device__ __forceinline__ bf16x8 vsplit(const short* lbase, int row, int c0, int hi) {
    const int r7 = row & 7;
    const int pc0 = c0 ^ r7, pc1 = (c0 + 1) ^ r7;
    const unsigned* b = (const unsigned*)(lbase + row * 64);
    const int o0 = pc0 * 4 + hi * 2;   // dword offset within the 32-dword row
    const int o1 = pc1 * 4 + hi * 2;
    union { unsigned u[4]; bf16x8 v; } t;
    t.u[0] = b[o0]; t.u[1] = b[o0 + 1];
    t.u[2] = b[o1]; t.u[3] = b[o1 + 1];
    return t.v;
}

// ---------------------------------------------------------------------------
// gemm128 core: C[128x128] = A[128x384] · B[128x384]^T, both k-contig rows,
// stride CCH. SINGLE-buffered phased loop (stage -> bar -> compute -> bar),
// 32 KB LDS -> 3 blocks/CU. Cross-block wave overlap (m114) replaces the
// intra-block double buffer. S layout: A at S[0..8191], B at S[8192..16383].
// ---------------------------------------------------------------------------
__device__ __forceinline__ void gemm128_core(
    const short* __restrict__ Ag, const short* __restrict__ Bg,
    short* S, f32x4 acc[4][4])
{
    const int tid = threadIdx.x, lane = tid & 63;
    const int l15 = tid & 15, quad = (tid >> 4) & 3, wv = tid >> 6;

#pragma unroll
    for (int kc = 0; kc < 6; ++kc) {
        stage_tile(Ag + kc * 64, CCH, S, wv, lane);
        stage_tile(Ag + kc * 64 + 64 * CCH, CCH, S + 4096, wv, lane);
        stage_tile(Bg + kc * 64, CCH, S + 8192, wv, lane);
        stage_tile(Bg + kc * 64 + 64 * CCH, CCH, S + 12288, wv, lane);
        __syncthreads();
        const short* Atile = S + (wv >> 1) * 4096;          // wi tile
        const short* Btile = S + 8192 + (wv & 1) * 4096;    // wj tile
#pragma unroll
        for (int h = 0; h < 2; ++h) {
            bf16x8 a[4], b[4];
#pragma unroll
            for (int s = 0; s < 4; ++s) {
                a[s] = frag_read(Atile, s * 16 + l15, h * 4 + quad);
                b[s] = frag_read(Btile, s * 16 + l15, h * 4 + quad);
            }
#pragma unroll
            for (int si = 0; si < 4; ++si)
#pragma unroll
                for (int sj = 0; sj < 4; ++sj)
                    acc[si][sj] = MFMA16(a[si], b[sj], acc[si][sj]);
        }
        __syncthreads();
    }
}

// Epilogue: repack the 128x128 bf16 C-tile through cbuf (= the 32 KB SMEM,
// free after the K-loop) so global stores are b128.
__device__ __forceinline__ void epilogue_bf16(
    f32x4 acc[4][4], short* cbuf,
    short* __restrict__ out, size_t obase, int ostride)
{
    const int tid = threadIdx.x;
    const int l15 = tid & 15, quad = (tid >> 4) & 3, wv = tid >> 6;
    const int wi = (wv >> 1) * 64, wj = (wv & 1) * 64;
    __syncthreads();
#pragma unroll
    for (int si = 0; si < 4; ++si)
#pragma unroll
        for (int sj = 0; sj < 4; ++sj)
#pragma unroll
            for (int rr = 0; rr < 4; ++rr)
                cbuf[(wi + si * 16 + quad * 4 + rr) * 128 + wj + sj * 16 + l15] =
                    f2b(acc[si][sj][rr]);
    __syncthreads();
#pragma unroll
    for (int pass = 0; pass < 8; ++pass) {
        const int row = pass * 16 + (tid >> 4);     // 0..127
        bf16x8 vchunk = *(const bf16x8*)(cbuf + row * 128 + l15 * 8);
        *(bf16x8*)(out + obase + (size_t)row * ostride + l15 * 8) = vchunk;
    }
}

// ---------------------------------------------------------------------------
// prep: fused transpose+convert (id<1536), weight convert (id<2112),
// amap zero (id>=2112). grid 2120.
// ---------------------------------------------------------------------------
__global__ __launch_bounds__(256) void prep(
    const float* __restrict__ Xq, const float* __restrict__ Xc,
    const float* __restrict__ w0, const float* __restrict__ w1,
    const float* __restrict__ w2, const float* __restrict__ w3,
    short* __restrict__ Xtq, short* __restrict__ Xtc,
    short* __restrict__ o0, short* __restrict__ o1,
    short* __restrict__ o2, short* __restrict__ o3,
    float* __restrict__ amap)
{
    __shared__ float tile[64][65];
    const int id = blockIdx.x, tid = threadIdx.x;
    if (id < 1536) {
        const int zz = id % 16, t = id / 16;
        const int n0 = (t % 16) * 64, c0 = (t / 16) * 64;
        const float* X = (zz < 8) ? Xq : Xc;
        short* Xt      = (zz < 8) ? Xtq : Xtc;
        const int b = zz & 7;
        const int tx = tid & 15, ty = tid >> 4;
#pragma unroll
        for (int rr = 0; rr < 4; ++rr) {
            const int c = rr * 16 + ty;
            float4 v = *(const float4*)&X[((size_t)(b * CCH + c0 + c)) * NTOK + n0 + tx * 4];
            tile[c][tx * 4 + 0] = v.x; tile[c][tx * 4 + 1] = v.y;
            tile[c][tx * 4 + 2] = v.z; tile[c][tx * 4 + 3] = v.w;
        }
        __syncthreads();
        const int n = tid >> 2, cb = (tid & 3) * 16;
        short tmp[16];
#pragma unroll
        for (int cc = 0; cc < 16; ++cc) tmp[cc] = f2b(tile[cb + cc][n]);
        short* dst = &Xt[((size_t)(b * NTOK + n0 + n)) * CCH + c0 + cb];
        *(int4*)dst = *(int4*)&tmp[0];
        *(int4*)(dst + 8) = *(int4*)&tmp[8];
    } else if (id < 2112) {
        const int w = id - 1536;
        const int which = w / 144;
        const int idx = (w % 144) * 256 + tid;
        const float* s = which == 0 ? w0 : which == 1 ? w1 : which == 2 ? w2 : w3;
        short* d       = which == 0 ? o0 : which == 1 ? o1 : which == 2 ? o2 : o3;
        float4 v = ((const float4*)s)[idx];
        short4 o = make_short4(f2b(v.x), f2b(v.y), f2b(v.z), f2b(v.w));
        ((short4*)d)[idx] = o;
    } else {
        const int o = (id - 2112) * 1024 + tid * 4;
        float4 z = {0.f, 0.f, 0.f, 0.f};
        *(float4*)&amap[o] = z;
    }
}

// ---------------------------------------------------------------------------
// Fused QKV projection, 128x128 tiles. 576 blocks: b=id%8 (XCD-local),
// r=id/8: which=r/24 (0:Q,1:K tok-major; 2:V ch-major), tt=r%24.
// Q output pre-scaled by QSCALE. 32 KB LDS -> one residency round.
// ---------------------------------------------------------------------------
__global__ __launch_bounds__(256, 3) void gemm_qkv(
    const short* __restrict__ xtq, const short* __restrict__ xtc,
    const short* __restrict__ wq, const short* __restrict__ wk,
    const short* __restrict__ wvm,
    short* __restrict__ qout, short* __restrict__ kout, short* __restrict__ vout)
{
    __shared__ __align__(16) short SMEM[16384];   // 32 KB: A | B, cbuf in epi
    const int id = blockIdx.x;
    const int b = id & 7, r = id >> 3;
    const int which = r / 24, tt = r % 24;

    const short *Ag, *Bg;
    short* out;
    size_t obase;
    int ostride;
    if (which < 2) {
        const int it = tt / 3, jt = tt % 3;
        const short* x = (which == 0) ? xtq : xtc;
        const short* W = (which == 0) ? wq : wk;
        Ag = x + ((size_t)(b * NTOK + it * 128)) * CCH;
        Bg = W + (size_t)(jt * 128) * CCH;
        out = (which == 0) ? qout : kout;
        obase = ((size_t)(b * NTOK + it * 128)) * CCH + jt * 128;
        ostride = CCH;
    } else {
        const int ct = tt % 3, nt = tt / 3;
        Ag = wvm + (size_t)(ct * 128) * CCH;
        Bg = xtc + ((size_t)(b * NTOK + nt * 128)) * CCH;
        out = vout;
        obase = ((size_t)(b * CCH + ct * 128)) * NTOK + nt * 128;
        ostride = NTOK;
    }

    f32x4 z4 = {0.f, 0.f, 0.f, 0.f};
    f32x4 acc[4][4];
#pragma unroll
    for (int si = 0; si < 4; ++si)
#pragma unroll
        for (int sj = 0; sj < 4; ++sj) acc[si][sj] = z4;

    gemm128_core(Ag, Bg, &SMEM[0], acc);

    if (which == 0) {
#pragma unroll
        for (int si = 0; si < 4; ++si)
#pragma unroll
            for (int sj = 0; sj < 4; ++sj)
#pragma unroll
                for (int rr = 0; rr < 4; ++rr)
                    acc[si][sj][rr] *= QSCALE;
    }
    epilogue_bf16(acc, &SMEM[0], out, obase, ostride);
}

// ---------------------------------------------------------------------------
// Attention O-pass — REVERTED to the r8-verified version (137.6 µs config):
// 768 blocks, 256 threads, i-tile 64, swapped-QK^T 32x32 MFMA, in-register P
// (vsplit pairing, r2), jsub-split compute (r4), counted-vmcnt ring-3 + raw
// s_barrier (r8), setprio (r7), obuf aliased onto the dead V ring (r5).
// r11's i-tile-128 variant regressed: 384 blocks on 256 CUs = 1.5/CU load
// imbalance (makespan = 2-block CUs) ate the halved-staging gain.
// No ds_write crosses a raw s_barrier here (only vmcnt-tracked
// global_load_lds; denbuf/rden_sh use full __syncthreads).
// ---------------------------------------------------------------------------
__global__ __launch_bounds__(256, 3) void attn(
    const short* __restrict__ qt, const short* __restrict__ kt,
    const short* __restrict__ vc, short* __restrict__ omid,
    float* __restrict__ rws)
{
    __shared__ __align__(16) short Kst[3][4096];   // 24 KB (64 tok x 64 ch)
    __shared__ __align__(16) short Vst[3][4096];   // 24 KB; obuf alias in epi
    __shared__ float denbuf[4][64];                // 1 KB
    __shared__ float rden_sh[2][32];
    float (*obuf)[16][64] = (float (*)[16][64])(&Vst[0][0]);  // 16 KB alias

    const int tid = threadIdx.x, lane = tid & 63;
    const int l31 = lane & 31, hi = lane >> 5;
    const int wv = tid >> 6;
    const int isub = (wv & 1) * 32;
    const int js = wv >> 1;            // this wave's fixed jsub

    const int id = blockIdx.x;
    const int b = id & 7, rr_ = id >> 3;
    const int h = rr_ % 6, i0 = (rr_ / 6) * 64;

    const size_t hoff = (size_t)b * NTOK * CCH + h * DHEAD;
    const short* Kg = kt + hoff;                                   // stride CCH
    const short* Vg = vc + ((size_t)(b * CCH + h * DHEAD)) * NTOK; // stride NTOK

    // Q B-frags hoisted: lane holds Q[i = i0+isub+l31, d = m*16 + hi*8 ..+8]
    const short* qp = qt + hoff + (size_t)(i0 + isub + l31) * CCH + hi * 8;
    bf16x8 qf[4];
#pragma unroll
    for (int m = 0; m < 4; ++m) qf[m] = *(const bf16x8*)(qp + m * 16);

    // prologue: tile0 by all waves (4 loads/thread), tile1 js-split (4 more).
    stage_tile(Kg, CCH, Kst[0], wv, lane);
    stage_tile(Vg, NTOK, Vst[0], wv, lane);
    if (js == 0)
        stage_tile_2w(Kg + (size_t)64 * CCH, CCH, Kst[1], wv & 1, lane);
    else
        stage_tile_2w(Vg + 64, NTOK, Vst[1], wv & 1, lane);
    asm volatile("s_waitcnt vmcnt(4)" ::: "memory");   // tile0 landed; tile1 in flight
    __builtin_amdgcn_sched_barrier(0);
    __builtin_amdgcn_s_barrier();
    __builtin_amdgcn_sched_barrier(0);

    const f32x16 z16 = {0,0,0,0,0,0,0,0,0,0,0,0,0,0,0,0};
    f32x16 oacc0 = z16, oacc1 = z16;   // d 0..31 / 32..63
    float den = 0.f;

    for (int jt = 0; jt < 16; ++jt) {
        const int cur = jt % 3;
        // stage tile jt+2 into ring slot (jt+2)%3 (last read in phase jt-1)
        if (jt < 14) {
            const int nxt = (jt + 2) % 3;
            if (js == 0)
                stage_tile_2w(Kg + (size_t)(jt + 2) * 64 * CCH, CCH,
                              Kst[nxt], wv & 1, lane);
            else
                stage_tile_2w(Vg + (size_t)(jt + 2) * 64, NTOK,
                              Vst[nxt], wv & 1, lane);
        }
        // compute this wave's jsub on tile jt
        {
            const short* Kb = Kst[cur];
            const short* Vb = Vst[cur];
            __builtin_amdgcn_s_setprio(1);
            f32x16 s = z16;
#pragma unroll
            for (int m = 0; m < 4; ++m)
                s = MFMA32(frag_read(Kb, js * 32 + l31, 2 * m + hi), qf[m], s);
            bf16x8 pa0, pa1;
#pragma unroll
            for (int e = 0; e < 8; ++e) {
                const float x0 = EXP2(s[e]);
                const float x1 = EXP2(s[8 + e]);
                den += x0 + x1;
                pa0[e] = (__bf16)x0;
                pa1[e] = (__bf16)x1;
            }
            oacc0 = MFMA32(pa0, vsplit(Vb, l31,      js * 4,     hi), oacc0);
            oacc0 = MFMA32(pa1, vsplit(Vb, l31,      js * 4 + 2, hi), oacc0);
            oacc1 = MFMA32(pa0, vsplit(Vb, 32 + l31, js * 4,     hi), oacc1);
            oacc1 = MFMA32(pa1, vsplit(Vb, 32 + l31, js * 4 + 2, hi), oacc1);
            __builtin_amdgcn_s_setprio(0);
        }
        // end of phase: wait ONLY tile-jt+1 loads (issued a full phase ago);
        // the 4 newest (tile jt+2) stay in flight across the barrier.
        if (jt < 13)
            asm volatile("s_waitcnt vmcnt(4)" ::: "memory");
        else
            asm volatile("s_waitcnt vmcnt(0)" ::: "memory");
        __builtin_amdgcn_sched_barrier(0);
        __builtin_amdgcn_s_barrier();
        __builtin_amdgcn_sched_barrier(0);
    }
    __syncthreads();   // full drain + fence before obuf aliases Vst

    // ---- epilogue: cross-js combine, normalize, store (verified r2/r5) ----
    const int dh = js;                 // this wave finalizes d-half dh
    if (dh == 0) {
#pragma unroll
        for (int g2 = 0; g2 < 16; ++g2) obuf[wv][g2][lane] = oacc1[g2];
    } else {
#pragma unroll
        for (int g2 = 0; g2 < 16; ++g2) obuf[wv][g2][lane] = oacc0[g2];
    }
    denbuf[wv][lane] = den;
    __syncthreads();

    const int g = wv & 1;
    const float dtot = denbuf[g][l31] + denbuf[g][l31 + 32]
                     + denbuf[g | 2][l31] + denbuf[g | 2][l31 + 32];
    const float rden = 1.0f / dtot;
    if (wv < 2 && lane < 32) {
        rden_sh[wv][lane] = rden;
        rws[((b * 6 + h) << 10) + i0 + isub + lane] = rden;
    }
    __syncthreads();

#pragma unroll
    for (int reg = 0; reg < 16; ++reg) {
        const int crw = (reg & 3) + 8 * (reg >> 2) + 4 * hi;     // i-local 0..31
        const float rd = rden_sh[g][crw];
        const float okeep = (dh == 0) ? oacc0[reg] : oacc1[reg];
        const float ov = (okeep + obuf[wv ^ 2][reg][lane]) * rd;
        omid[((size_t)(b * NTOK + i0 + isub + crw)) * CCH + h * DHEAD + dh * 32 + l31] =
            f2b(ov);
    }
}

// ---------------------------------------------------------------------------
// tail_k: o_proj (id<192) + amap (id>=192) merged (verified r7). The 1536
// short amap blocks backfill the CUs o_proj leaves idle.
// amap ring-3 with the r11 RACE FIX: colbuf3 is written via ds_write and
// read by other waves after a raw s_barrier — raw s_barrier does NOT wait
// LDS writes, so the end-of-phase waits include lgkmcnt(0) (r10's failure
// was exactly this missing drain). vmcnt counting unchanged (r8-verified).
// ---------------------------------------------------------------------------
__global__ __launch_bounds__(256, 3) void tail_k(
    const short* __restrict__ wo, const short* __restrict__ omid,
    const float* __restrict__ bias, float* __restrict__ Y,
    const short* __restrict__ qt, const short* __restrict__ kt,
    const float* __restrict__ rws, float* __restrict__ amap)
{
    __shared__ __align__(16) short SMEM[16384];   // 32 KB
    const int id = blockIdx.x, tid = threadIdx.x;

    if (id < 192) {
        // ---------------- o_proj part (verbatim r6) ----------------
        const int b = id & 7, r = id >> 3;
        const int ct = r % 3, nt = r / 3;

        const short* Ag = wo + (size_t)(ct * 128) * CCH;
        const short* Bg = omid + ((size_t)(b * NTOK + nt * 128)) * CCH;

        f32x4 z4 = {0.f, 0.f, 0.f, 0.f};
        f32x4 acc[4][4];
#pragma unroll
        for (int si = 0; si < 4; ++si)
#pragma unroll
            for (int sj = 0; sj < 4; ++sj) acc[si][sj] = z4;

        gemm128_core(Ag, Bg, &SMEM[0], acc);

        const int l15 = tid & 15, quad = (tid >> 4) & 3, wv = tid >> 6;
        const int wi = (wv >> 1) * 64, wj = (wv & 1) * 64;
#pragma unroll
        for (int si = 0; si < 4; ++si) {
#pragma unroll
            for (int rr = 0; rr < 4; ++rr) {
                const int ch = ct * 128 + wi + si * 16 + quad * 4 + rr;
                const float bv = bias[ch];
#pragma unroll
                for (int sj = 0; sj < 4; ++sj)
                    Y[((size_t)(b * CCH + ch)) * NTOK + nt * 128 + wj + sj * 16 + l15] =
                        acc[si][sj][rr] + bv;
            }
        }
    } else {
        // ------------- amap part (r6 body + r8 T4 ring-3, race-fixed) -----
        short* Kst3 = &SMEM[0];                                    // 3 x 8 KB
        float (*colbuf3)[4][64] = (float (*)[4][64])(&SMEM[12288]); // 3 KB

        const int lane = tid & 63;
        const int l15 = tid & 15, quad = (tid >> 4) & 3, wv = tid >> 6;
        const int aid = id - 192;
        const int b = aid & 7, r = aid >> 3;        // r in 0..191
        const int h = r % 6, q = r / 6;             // q in 0..31
        const int i0 = (q >> 1) * 64;
        const int jt0 = (q & 1) * 8;

        const size_t hoff = (size_t)b * NTOK * CCH + h * DHEAD;
        const short* Kg = kt + hoff;
        const short* qp = qt + hoff + (size_t)(i0 + wv * 16 + l15) * CCH + quad * 8;
        const bf16x8 qa0 = *(const bf16x8*)qp;
        const bf16x8 qa1 = *(const bf16x8*)(qp + 32);

        float rdl[4];
#pragma unroll
        for (int rr = 0; rr < 4; ++rr)
            rdl[rr] = rws[((b * 6 + h) << 10) + i0 + wv * 16 + quad * 4 + rr];

        // prologue: tiles jt0, jt0+1 into slots 0,1 (2+2 gld/thread)
        stage_tile(Kg + (size_t)jt0 * 64 * CCH, CCH, Kst3, wv, lane);
        stage_tile(Kg + (size_t)(jt0 + 1) * 64 * CCH, CCH, Kst3 + 4096, wv, lane);
        asm volatile("s_waitcnt vmcnt(2)" ::: "memory");
        __builtin_amdgcn_sched_barrier(0);
        __builtin_amdgcn_s_barrier();
        __builtin_amdgcn_sched_barrier(0);

        for (int t = 0; t < 8; ++t) {
            const int jt = jt0 + t;
            const int cur = t % 3;
            if (t < 6)
                stage_tile(Kg + (size_t)(jt + 2) * 64 * CCH, CCH,
                           Kst3 + ((t + 2) % 3) * 4096, wv, lane);
            const short* Kb = Kst3 + cur * 4096;
            f32x4 z4 = {0.f, 0.f, 0.f, 0.f};
            f32x4 s[4] = {z4, z4, z4, z4};
#pragma unroll
            for (int ns = 0; ns < 4; ++ns) {
                const int row = ns * 16 + l15;
                bf16x8 k0 = frag_read(Kb, row, quad);
                bf16x8 k1 = frag_read(Kb, row, quad + 4);
                s[ns] = MFMA16(qa0, k0, s[ns]);
                s[ns] = MFMA16(qa1, k1, s[ns]);
            }
#pragma unroll
            for (int ns = 0; ns < 4; ++ns) {
                float cs = EXP2(s[ns][0]) * rdl[0] + EXP2(s[ns][1]) * rdl[1]
                         + EXP2(s[ns][2]) * rdl[2] + EXP2(s[ns][3]) * rdl[3];
                cs += __shfl_xor(cs, 16);
                cs += __shfl_xor(cs, 32);
                if (quad == 0) colbuf3[cur][wv][ns * 16 + l15] = cs;
            }
            // RACE FIX: lgkmcnt(0) drains the colbuf3 ds_writes before the
            // raw barrier (vmcnt covers only the global_load_lds staging).
            if (t < 6)
                asm volatile("s_waitcnt vmcnt(2) lgkmcnt(0)" ::: "memory");
            else
                asm volatile("s_waitcnt vmcnt(0) lgkmcnt(0)" ::: "memory");
            __builtin_amdgcn_sched_barrier(0);
            __builtin_amdgcn_s_barrier();
            __builtin_amdgcn_sched_barrier(0);
            if (tid < 64) {
                const float tsum = colbuf3[cur][0][tid] + colbuf3[cur][1][tid]
                                 + colbuf3[cur][2][tid] + colbuf3[cur][3][tid];
                atomicAdd(amap + (size_t)b * NTOK + jt * 64 + tid,
                          tsum * (1.0f / (HEADS * NTOK)));
            }
        }
    }
}

// ---------------------------------------------------------------------------
extern "C" void kernel_launch(void* const* d_in, const int* in_sizes, int n_in,
                              void* d_out, int out_size, void* d_ws, size_t ws_size,
                              hipStream_t stream)
{
    const float* query   = (const float*)d_in[0];
    const float* context = (const float*)d_in[1];
    const float* Wq      = (const float*)d_in[2];
    const float* Wk      = (const float*)d_in[3];
    const float* Wv      = (const float*)d_in[4];
    const float* Wo      = (const float*)d_in[5];
    const float* bo      = (const float*)d_in[6];

    float* out = (float*)d_out;                          // [8,384,1024] fp32
    const size_t out_elems = (size_t)BATCH * CCH * NTOK;
    float* attn_map = out + out_elems;                   // [8,1024] fp32

    short* ws = (short*)d_ws;
    const size_t XT = (size_t)BATCH * NTOK * CCH;
    const size_t WSZ = (size_t)CCH * CCH;
    short* xtq  = ws;
    short* xtc  = xtq + XT;
    short* wqb  = xtc + XT;
    short* wkb  = wqb + WSZ;
    short* wvb  = wkb + WSZ;
    short* wob  = wvb + WSZ;
    short* qtb  = wob + WSZ;
    short* ktb  = qtb + XT;
    short* vcb  = ktb + XT;
    short* omid = vcb + XT;
    float* rws  = (float*)(omid + XT);                   // [8*6*1024] fp32 rden

    const dim3 blk(256);

    prep<<<dim3(2120), blk, 0, stream>>>(query, context, Wq, Wk, Wv, Wo,
                                         xtq, xtc, wqb, wkb, wvb, wob, attn_map);

    gemm_qkv<<<dim3(576), blk, 0, stream>>>(xtq, xtc, wqb, wkb, wvb,
                                            qtb, ktb, vcb);

    attn<<<dim3(768), blk, 0, stream>>>(qtb, ktb, vcb, omid, rws);

    tail_k<<<dim3(1728), blk, 0, stream>>>(wob, omid, bo, out,
                                           qtb, ktb, rws, attn_map);
}

// Round 13
// 137.267 us; speedup vs baseline: 1.0379x; 1.0128x over previous
//
#include <hip/hip_runtime.h>

// Problem constants
#define BATCH 8
#define CCH   384      // channels C == INNER
#define NTOK  1024     // H*W
#define HEADS 6
#define DHEAD 64
// softmax scale 1/8 and log2(e) folded into Q at projection time:
// qout = Q * 0.125 * 1.4426950408889634, attn uses exp2(s) = bare v_exp.
#define QSCALE 0.18033688011112042f

typedef __bf16 bf16x8 __attribute__((ext_vector_type(8)));
typedef float  f32x4  __attribute__((ext_vector_type(4)));
typedef float  f32x16 __attribute__((ext_vector_type(16)));

#define MFMA16(a, b, c) __builtin_amdgcn_mfma_f32_16x16x32_bf16((a), (b), (c), 0, 0, 0)
#define MFMA32(a, b, c) __builtin_amdgcn_mfma_f32_32x32x16_bf16((a), (b), (c), 0, 0, 0)
#define EXP2(x) __builtin_amdgcn_exp2f(x)

// fp32 -> bf16 RNE, raw bits
__device__ __forceinline__ short f2b(float x) {
    unsigned u = __float_as_uint(x);
    u += 0x7fffu + ((u >> 16) & 1u);
    return (short)(u >> 16);
}

// async global->LDS, 16B/lane. LDS dst = wave-uniform base + lane*16.
__device__ __forceinline__ void gld_lds16(const short* gp, short* lp) {
    __builtin_amdgcn_global_load_lds(
        (const __attribute__((address_space(1))) void*)gp,
        (__attribute__((address_space(3))) void*)lp, 16, 0, 0);
}

// ---- 64x64 xor-swizzled tile staging (4 waves) — verified r3/r4 ----
__device__ __forceinline__ void stage_tile(const short* gbase, size_t gstride,
                                           short* lbase, int wv, int lane) {
#pragma unroll
    for (int t = 0; t < 2; ++t) {
        const int row = t * 8 + (lane >> 3);
        const int c   = (lane & 7) ^ (row & 7);
        gld_lds16(gbase + (size_t)(wv * 16 + row) * gstride + c * 8,
                  lbase + (wv * 16 + t * 8) * 64);
    }
}
// same tile, staged by 2 waves (sw = 0/1), 4 gld per thread
__device__ __forceinline__ void stage_tile_2w(const short* gbase, size_t gstride,
                                              short* lbase, int sw, int lane) {
#pragma unroll
    for (int t = 0; t < 4; ++t) {
        const int row = sw * 32 + t * 8 + (lane >> 3);
        const int c   = (lane & 7) ^ (row & 7);
        gld_lds16(gbase + (size_t)row * gstride + c * 8,
                  lbase + (sw * 32 + t * 8) * 64);
    }
}
__device__ __forceinline__ bf16x8 frag_read(const short* lbase, int row, int c) {
    const int pc = c ^ (row & 7);
    return *(const bf16x8*)(lbase + row * 64 + pc * 8);
}

// Split V fragment read: element e of result holds V[row][tok], tok matching
// the NATURAL post-QK P register order: slots (hi, e) <-> j_local =
// [0,1,2,3,8,9,10,11][e] + 4*hi within the 16-token chunk starting at c0*8.
// Two 8B reads: chunk c0 half hi, chunk c0+1 half hi (xor-swizzled rows).
__device__ __forceinline__ bf16x8 vsplit(const short* lbase, int row, int c0, int hi) {
    const int r7 = row & 7;
    const int pc0 = c0 ^ r7, pc1 = (c0 + 1) ^ r7;
    const unsigned* b = (const unsigned*)(lbase + row * 64);
    const int o0 = pc0 * 4 + hi * 2;   // dword offset within the 32-dword row
    const int o1 = pc1 * 4 + hi * 2;
    union { unsigned u[4]; bf16x8 v; } t;
    t.u[0] = b[o0]; t.u[1] = b[o0 + 1];
    t.u[2] = b[o1]; t.u[3] = b[o1 + 1];
    return t.v;
}

// ---------------------------------------------------------------------------
// gemm128 core: C[128x128] = A[128x384] · B[128x384]^T, both k-contig rows,
// stride CCH. SINGLE-buffered phased loop (stage -> bar -> compute -> bar),
// 32 KB LDS -> 3 blocks/CU. Cross-block wave overlap (m114) replaces the
// intra-block double buffer. S layout: A at S[0..8191], B at S[8192..16383].
// ---------------------------------------------------------------------------
__device__ __forceinline__ void gemm128_core(
    const short* __restrict__ Ag, const short* __restrict__ Bg,
    short* S, f32x4 acc[4][4])
{
    const int tid = threadIdx.x, lane = tid & 63;
    const int l15 = tid & 15, quad = (tid >> 4) & 3, wv = tid >> 6;

#pragma unroll
    for (int kc = 0; kc < 6; ++kc) {
        stage_tile(Ag + kc * 64, CCH, S, wv, lane);
        stage_tile(Ag + kc * 64 + 64 * CCH, CCH, S + 4096, wv, lane);
        stage_tile(Bg + kc * 64, CCH, S + 8192, wv, lane);
        stage_tile(Bg + kc * 64 + 64 * CCH, CCH, S + 12288, wv, lane);
        __syncthreads();
        const short* Atile = S + (wv >> 1) * 4096;          // wi tile
        const short* Btile = S + 8192 + (wv & 1) * 4096;    // wj tile
#pragma unroll
        for (int h = 0; h < 2; ++h) {
            bf16x8 a[4], b[4];
#pragma unroll
            for (int s = 0; s < 4; ++s) {
                a[s] = frag_read(Atile, s * 16 + l15, h * 4 + quad);
                b[s] = frag_read(Btile, s * 16 + l15, h * 4 + quad);
            }
#pragma unroll
            for (int si = 0; si < 4; ++si)
#pragma unroll
                for (int sj = 0; sj < 4; ++sj)
                    acc[si][sj] = MFMA16(a[si], b[sj], acc[si][sj]);
        }
        __syncthreads();
    }
}

// Epilogue: repack the 128x128 bf16 C-tile through cbuf (= the 32 KB SMEM,
// free after the K-loop) so global stores are b128.
__device__ __forceinline__ void epilogue_bf16(
    f32x4 acc[4][4], short* cbuf,
    short* __restrict__ out, size_t obase, int ostride)
{
    const int tid = threadIdx.x;
    const int l15 = tid & 15, quad = (tid >> 4) & 3, wv = tid >> 6;
    const int wi = (wv >> 1) * 64, wj = (wv & 1) * 64;
    __syncthreads();
#pragma unroll
    for (int si = 0; si < 4; ++si)
#pragma unroll
        for (int sj = 0; sj < 4; ++sj)
#pragma unroll
            for (int rr = 0; rr < 4; ++rr)
                cbuf[(wi + si * 16 + quad * 4 + rr) * 128 + wj + sj * 16 + l15] =
                    f2b(acc[si][sj][rr]);
    __syncthreads();
#pragma unroll
    for (int pass = 0; pass < 8; ++pass) {
        const int row = pass * 16 + (tid >> 4);     // 0..127
        bf16x8 vchunk = *(const bf16x8*)(cbuf + row * 128 + l15 * 8);
        *(bf16x8*)(out + obase + (size_t)row * ostride + l15 * 8) = vchunk;
    }
}

// ---------------------------------------------------------------------------
// prep: fused transpose+convert (id<1536), weight convert (id<2112),
// amap zero (id>=2112). grid 2120.
// ---------------------------------------------------------------------------
__global__ __launch_bounds__(256) void prep(
    const float* __restrict__ Xq, const float* __restrict__ Xc,
    const float* __restrict__ w0, const float* __restrict__ w1,
    const float* __restrict__ w2, const float* __restrict__ w3,
    short* __restrict__ Xtq, short* __restrict__ Xtc,
    short* __restrict__ o0, short* __restrict__ o1,
    short* __restrict__ o2, short* __restrict__ o3,
    float* __restrict__ amap)
{
    __shared__ float tile[64][65];
    const int id = blockIdx.x, tid = threadIdx.x;
    if (id < 1536) {
        const int zz = id % 16, t = id / 16;
        const int n0 = (t % 16) * 64, c0 = (t / 16) * 64;
        const float* X = (zz < 8) ? Xq : Xc;
        short* Xt      = (zz < 8) ? Xtq : Xtc;
        const int b = zz & 7;
        const int tx = tid & 15, ty = tid >> 4;
#pragma unroll
        for (int rr = 0; rr < 4; ++rr) {
            const int c = rr * 16 + ty;
            float4 v = *(const float4*)&X[((size_t)(b * CCH + c0 + c)) * NTOK + n0 + tx * 4];
            tile[c][tx * 4 + 0] = v.x; tile[c][tx * 4 + 1] = v.y;
            tile[c][tx * 4 + 2] = v.z; tile[c][tx * 4 + 3] = v.w;
        }
        __syncthreads();
        const int n = tid >> 2, cb = (tid & 3) * 16;
        short tmp[16];
#pragma unroll
        for (int cc = 0; cc < 16; ++cc) tmp[cc] = f2b(tile[cb + cc][n]);
        short* dst = &Xt[((size_t)(b * NTOK + n0 + n)) * CCH + c0 + cb];
        *(int4*)dst = *(int4*)&tmp[0];
        *(int4*)(dst + 8) = *(int4*)&tmp[8];
    } else if (id < 2112) {
        const int w = id - 1536;
        const int which = w / 144;
        const int idx = (w % 144) * 256 + tid;
        const float* s = which == 0 ? w0 : which == 1 ? w1 : which == 2 ? w2 : w3;
        short* d       = which == 0 ? o0 : which == 1 ? o1 : which == 2 ? o2 : o3;
        float4 v = ((const float4*)s)[idx];
        short4 o = make_short4(f2b(v.x), f2b(v.y), f2b(v.z), f2b(v.w));
        ((short4*)d)[idx] = o;
    } else {
        const int o = (id - 2112) * 1024 + tid * 4;
        float4 z = {0.f, 0.f, 0.f, 0.f};
        *(float4*)&amap[o] = z;
    }
}

// ---------------------------------------------------------------------------
// Fused QKV projection, 128x128 tiles. 576 blocks: b=id%8 (XCD-local),
// r=id/8: which=r/24 (0:Q,1:K tok-major; 2:V ch-major), tt=r%24.
// Q output pre-scaled by QSCALE. 32 KB LDS -> one residency round.
// ---------------------------------------------------------------------------
__global__ __launch_bounds__(256, 3) void gemm_qkv(
    const short* __restrict__ xtq, const short* __restrict__ xtc,
    const short* __restrict__ wq, const short* __restrict__ wk,
    const short* __restrict__ wvm,
    short* __restrict__ qout, short* __restrict__ kout, short* __restrict__ vout)
{
    __shared__ __align__(16) short SMEM[16384];   // 32 KB: A | B, cbuf in epi
    const int id = blockIdx.x;
    const int b = id & 7, r = id >> 3;
    const int which = r / 24, tt = r % 24;

    const short *Ag, *Bg;
    short* out;
    size_t obase;
    int ostride;
    if (which < 2) {
        const int it = tt / 3, jt = tt % 3;
        const short* x = (which == 0) ? xtq : xtc;
        const short* W = (which == 0) ? wq : wk;
        Ag = x + ((size_t)(b * NTOK + it * 128)) * CCH;
        Bg = W + (size_t)(jt * 128) * CCH;
        out = (which == 0) ? qout : kout;
        obase = ((size_t)(b * NTOK + it * 128)) * CCH + jt * 128;
        ostride = CCH;
    } else {
        const int ct = tt % 3, nt = tt / 3;
        Ag = wvm + (size_t)(ct * 128) * CCH;
        Bg = xtc + ((size_t)(b * NTOK + nt * 128)) * CCH;
        out = vout;
        obase = ((size_t)(b * CCH + ct * 128)) * NTOK + nt * 128;
        ostride = NTOK;
    }

    f32x4 z4 = {0.f, 0.f, 0.f, 0.f};
    f32x4 acc[4][4];
#pragma unroll
    for (int si = 0; si < 4; ++si)
#pragma unroll
        for (int sj = 0; sj < 4; ++sj) acc[si][sj] = z4;

    gemm128_core(Ag, Bg, &SMEM[0], acc);

    if (which == 0) {
#pragma unroll
        for (int si = 0; si < 4; ++si)
#pragma unroll
            for (int sj = 0; sj < 4; ++sj)
#pragma unroll
                for (int rr = 0; rr < 4; ++rr)
                    acc[si][sj][rr] *= QSCALE;
    }
    epilogue_bf16(acc, &SMEM[0], out, obase, ostride);
}

// ---------------------------------------------------------------------------
// Attention O-pass — swapped-QK^T 32x32 MFMA, in-register P (vsplit pairing,
// verified r2), jsub-split compute (verified r4), obuf aliased onto Vst
// (verified r5), setprio (r7), counted-vmcnt ring-3 + raw s_barrier (r8,
// measured 137.6). Staging loads issued at phase top are for tile jt+2,
// consumed two phases later; end-of-phase wait is s_waitcnt vmcnt(4) (waits
// ONLY tile-jt+1 loads; newest 4 stay in flight across the barrier).
//  RAW: each wave waits its own 4 via vmcnt before s_barrier.       [ok]
//  WAR: top-of-jt writes buf (jt+2)%3 == buf read in phase jt-1;
//       separated by the end-of-(jt-1) barrier.                     [ok]
// No ds_write crosses a raw s_barrier here (only vmcnt-tracked
// global_load_lds; denbuf/rden_sh use full __syncthreads).
// ---------------------------------------------------------------------------
__global__ __launch_bounds__(256, 3) void attn(
    const short* __restrict__ qt, const short* __restrict__ kt,
    const short* __restrict__ vc, short* __restrict__ omid,
    float* __restrict__ rws)
{
    __shared__ __align__(16) short Kst[3][4096];   // 24 KB (64 tok x 64 ch)
    __shared__ __align__(16) short Vst[3][4096];   // 24 KB; obuf alias in epi
    __shared__ float denbuf[4][64];                // 1 KB
    __shared__ float rden_sh[2][32];
    float (*obuf)[16][64] = (float (*)[16][64])(&Vst[0][0]);  // 16 KB alias

    const int tid = threadIdx.x, lane = tid & 63;
    const int l31 = lane & 31, hi = lane >> 5;
    const int wv = tid >> 6;
    const int isub = (wv & 1) * 32;
    const int js = wv >> 1;            // this wave's fixed jsub

    const int id = blockIdx.x;
    const int b = id & 7, rr_ = id >> 3;
    const int h = rr_ % 6, i0 = (rr_ / 6) * 64;

    const size_t hoff = (size_t)b * NTOK * CCH + h * DHEAD;
    const short* Kg = kt + hoff;                                   // stride CCH
    const short* Vg = vc + ((size_t)(b * CCH + h * DHEAD)) * NTOK; // stride NTOK

    // Q B-frags hoisted: lane holds Q[i = i0+isub+l31, d = m*16 + hi*8 ..+8]
    const short* qp = qt + hoff + (size_t)(i0 + isub + l31) * CCH + hi * 8;
    bf16x8 qf[4];
#pragma unroll
    for (int m = 0; m < 4; ++m) qf[m] = *(const bf16x8*)(qp + m * 16);

    // prologue: tile0 by all waves (4 loads/thread), tile1 js-split (4 more).
    stage_tile(Kg, CCH, Kst[0], wv, lane);
    stage_tile(Vg, NTOK, Vst[0], wv, lane);
    if (js == 0)
        stage_tile_2w(Kg + (size_t)64 * CCH, CCH, Kst[1], wv & 1, lane);
    else
        stage_tile_2w(Vg + 64, NTOK, Vst[1], wv & 1, lane);
    asm volatile("s_waitcnt vmcnt(4)" ::: "memory");   // tile0 landed; tile1 in flight
    __builtin_amdgcn_sched_barrier(0);
    __builtin_amdgcn_s_barrier();
    __builtin_amdgcn_sched_barrier(0);

    const f32x16 z16 = {0,0,0,0,0,0,0,0,0,0,0,0,0,0,0,0};
    f32x16 oacc0 = z16, oacc1 = z16;   // d 0..31 / 32..63
    float den = 0.f;

    for (int jt = 0; jt < 16; ++jt) {
        const int cur = jt % 3;
        // stage tile jt+2 into ring slot (jt+2)%3 (last read in phase jt-1)
        if (jt < 14) {
            const int nxt = (jt + 2) % 3;
            if (js == 0)
                stage_tile_2w(Kg + (size_t)(jt + 2) * 64 * CCH, CCH,
                              Kst[nxt], wv & 1, lane);
            else
                stage_tile_2w(Vg + (size_t)(jt + 2) * 64, NTOK,
                              Vst[nxt], wv & 1, lane);
        }
        // compute this wave's jsub on tile jt
        {
            const short* Kb = Kst[cur];
            const short* Vb = Vst[cur];
            __builtin_amdgcn_s_setprio(1);
            f32x16 s = z16;
#pragma unroll
            for (int m = 0; m < 4; ++m)
                s = MFMA32(frag_read(Kb, js * 32 + l31, 2 * m + hi), qf[m], s);
            bf16x8 pa0, pa1;
#pragma unroll
            for (int e = 0; e < 8; ++e) {
                const float x0 = EXP2(s[e]);
                const float x1 = EXP2(s[8 + e]);
                den += x0 + x1;
                pa0[e] = (__bf16)x0;
                pa1[e] = (__bf16)x1;
            }
            oacc0 = MFMA32(pa0, vsplit(Vb, l31,      js * 4,     hi), oacc0);
            oacc0 = MFMA32(pa1, vsplit(Vb, l31,      js * 4 + 2, hi), oacc0);
            oacc1 = MFMA32(pa0, vsplit(Vb, 32 + l31, js * 4,     hi), oacc1);
            oacc1 = MFMA32(pa1, vsplit(Vb, 32 + l31, js * 4 + 2, hi), oacc1);
            __builtin_amdgcn_s_setprio(0);
        }
        // end of phase: wait ONLY tile-jt+1 loads (issued a full phase ago);
        // the 4 newest (tile jt+2) stay in flight across the barrier.
        if (jt < 13)
            asm volatile("s_waitcnt vmcnt(4)" ::: "memory");
        else
            asm volatile("s_waitcnt vmcnt(0)" ::: "memory");
        __builtin_amdgcn_sched_barrier(0);
        __builtin_amdgcn_s_barrier();
        __builtin_amdgcn_sched_barrier(0);
    }
    __syncthreads();   // full drain + fence before obuf aliases Vst

    // ---- epilogue: cross-js combine, normalize, store (verified r2/r5) ----
    const int dh = js;                 // this wave finalizes d-half dh
    if (dh == 0) {
#pragma unroll
        for (int g2 = 0; g2 < 16; ++g2) obuf[wv][g2][lane] = oacc1[g2];
    } else {
#pragma unroll
        for (int g2 = 0; g2 < 16; ++g2) obuf[wv][g2][lane] = oacc0[g2];
    }
    denbuf[wv][lane] = den;
    __syncthreads();

    const int g = wv & 1;
    const float dtot = denbuf[g][l31] + denbuf[g][l31 + 32]
                     + denbuf[g | 2][l31] + denbuf[g | 2][l31 + 32];
    const float rden = 1.0f / dtot;
    if (wv < 2 && lane < 32) {
        rden_sh[wv][lane] = rden;
        rws[((b * 6 + h) << 10) + i0 + isub + lane] = rden;
    }
    __syncthreads();

#pragma unroll
    for (int reg = 0; reg < 16; ++reg) {
        const int crw = (reg & 3) + 8 * (reg >> 2) + 4 * hi;     // i-local 0..31
        const float rd = rden_sh[g][crw];
        const float okeep = (dh == 0) ? oacc0[reg] : oacc1[reg];
        const float ov = (okeep + obuf[wv ^ 2][reg][lane]) * rd;
        omid[((size_t)(b * NTOK + i0 + isub + crw)) * CCH + h * DHEAD + dh * 32 + l31] =
            f2b(ov);
    }
}

// ---------------------------------------------------------------------------
// tail_k: o_proj (id<192) + amap (id>=192) merged (verified r7). The 1536
// short amap blocks backfill the CUs o_proj leaves idle.
// amap part: r8's verified __syncthreads double-buffer (the r12 A/B showed
// the ring-3 + lgkmcnt variant is neutral-to-negative — the mandatory
// lgkmcnt(0) drain negates the counted-vmcnt benefit).
// ---------------------------------------------------------------------------
__global__ __launch_bounds__(256, 3) void tail_k(
    const short* __restrict__ wo, const short* __restrict__ omid,
    const float* __restrict__ bias, float* __restrict__ Y,
    const short* __restrict__ qt, const short* __restrict__ kt,
    const float* __restrict__ rws, float* __restrict__ amap)
{
    __shared__ __align__(16) short SMEM[16384];   // 32 KB
    const int id = blockIdx.x, tid = threadIdx.x;

    if (id < 192) {
        // ---------------- o_proj part (verbatim r6) ----------------
        const int b = id & 7, r = id >> 3;
        const int ct = r % 3, nt = r / 3;

        const short* Ag = wo + (size_t)(ct * 128) * CCH;
        const short* Bg = omid + ((size_t)(b * NTOK + nt * 128)) * CCH;

        f32x4 z4 = {0.f, 0.f, 0.f, 0.f};
        f32x4 acc[4][4];
#pragma unroll
        for (int si = 0; si < 4; ++si)
#pragma unroll
            for (int sj = 0; sj < 4; ++sj) acc[si][sj] = z4;

        gemm128_core(Ag, Bg, &SMEM[0], acc);

        const int l15 = tid & 15, quad = (tid >> 4) & 3, wv = tid >> 6;
        const int wi = (wv >> 1) * 64, wj = (wv & 1) * 64;
#pragma unroll
        for (int si = 0; si < 4; ++si) {
#pragma unroll
            for (int rr = 0; rr < 4; ++rr) {
                const int ch = ct * 128 + wi + si * 16 + quad * 4 + rr;
                const float bv = bias[ch];
#pragma unroll
                for (int sj = 0; sj < 4; ++sj)
                    Y[((size_t)(b * CCH + ch)) * NTOK + nt * 128 + wj + sj * 16 + l15] =
                        acc[si][sj][rr] + bv;
            }
        }
    } else {
        // ---------------- amap part (verbatim r6/r8, j-split) ----------------
        short (*Kst)[4096] = (short (*)[4096])(&SMEM[0]);           // 16 KB
        float (*colbuf)[4][64] = (float (*)[4][64])(&SMEM[8192]);   // 2 KB

        const int lane = tid & 63;
        const int l15 = tid & 15, quad = (tid >> 4) & 3, wv = tid >> 6;
        const int aid = id - 192;
        const int b = aid & 7, r = aid >> 3;        // r in 0..191
        const int h = r % 6, q = r / 6;             // q in 0..31
        const int i0 = (q >> 1) * 64;
        const int jt0 = (q & 1) * 8;

        const size_t hoff = (size_t)b * NTOK * CCH + h * DHEAD;
        const short* Kg = kt + hoff;
        const short* qp = qt + hoff + (size_t)(i0 + wv * 16 + l15) * CCH + quad * 8;
        const bf16x8 qa0 = *(const bf16x8*)qp;
        const bf16x8 qa1 = *(const bf16x8*)(qp + 32);

        float rdl[4];
#pragma unroll
        for (int rr = 0; rr < 4; ++rr)
            rdl[rr] = rws[((b * 6 + h) << 10) + i0 + wv * 16 + quad * 4 + rr];

        stage_tile(Kg + (size_t)jt0 * 64 * CCH, CCH, Kst[0], wv, lane);
        __syncthreads();

        for (int t = 0; t < 8; ++t) {
            const int jt = jt0 + t;
            const int cur = t & 1;
            if (t < 7)
                stage_tile(Kg + (size_t)(jt + 1) * 64 * CCH, CCH, Kst[cur ^ 1], wv, lane);
            f32x4 z4 = {0.f, 0.f, 0.f, 0.f};
            f32x4 s[4] = {z4, z4, z4, z4};
#pragma unroll
            for (int ns = 0; ns < 4; ++ns) {
                const int row = ns * 16 + l15;
                bf16x8 k0 = frag_read(Kst[cur], row, quad);
                bf16x8 k1 = frag_read(Kst[cur], row, quad + 4);
                s[ns] = MFMA16(qa0, k0, s[ns]);
                s[ns] = MFMA16(qa1, k1, s[ns]);
            }
#pragma unroll
            for (int ns = 0; ns < 4; ++ns) {
                float cs = EXP2(s[ns][0]) * rdl[0] + EXP2(s[ns][1]) * rdl[1]
                         + EXP2(s[ns][2]) * rdl[2] + EXP2(s[ns][3]) * rdl[3];
                cs += __shfl_xor(cs, 16);
                cs += __shfl_xor(cs, 32);
                if (quad == 0) colbuf[cur][wv][ns * 16 + l15] = cs;
            }
            __syncthreads();
            if (tid < 64) {
                const float tsum = colbuf[cur][0][tid] + colbuf[cur][1][tid]
                                 + colbuf[cur][2][tid] + colbuf[cur][3][tid];
                atomicAdd(amap + (size_t)b * NTOK + jt * 64 + tid,
                          tsum * (1.0f / (HEADS * NTOK)));
            }
        }
    }
}

// ---------------------------------------------------------------------------
extern "C" void kernel_launch(void* const* d_in, const int* in_sizes, int n_in,
                              void* d_out, int out_size, void* d_ws, size_t ws_size,
                              hipStream_t stream)
{
    const float* query   = (const float*)d_in[0];
    const float* context = (const float*)d_in[1];
    const float* Wq      = (const float*)d_in[2];
    const float* Wk      = (const float*)d_in[3];
    const float* Wv      = (const float*)d_in[4];
    const float* Wo      = (const float*)d_in[5];
    const float* bo      = (const float*)d_in[6];

    float* out = (float*)d_out;                          // [8,384,1024] fp32
    const size_t out_elems = (size_t)BATCH * CCH * NTOK;
    float* attn_map = out + out_elems;                   // [8,1024] fp32

    short* ws = (short*)d_ws;
    const size_t XT = (size_t)BATCH * NTOK * CCH;
    const size_t WSZ = (size_t)CCH * CCH;
    short* xtq  = ws;
    short* xtc  = xtq + XT;
    short* wqb  = xtc + XT;
    short* wkb  = wqb + WSZ;
    short* wvb  = wkb + WSZ;
    short* wob  = wvb + WSZ;
    short* qtb  = wob + WSZ;
    short* ktb  = qtb + XT;
    short* vcb  = ktb + XT;
    short* omid = vcb + XT;
    float* rws  = (float*)(omid + XT);                   // [8*6*1024] fp32 rden

    const dim3 blk(256);

    prep<<<dim3(2120), blk, 0, stream>>>(query, context, Wq, Wk, Wv, Wo,
                                         xtq, xtc, wqb, wkb, wvb, wob, attn_map);

    gemm_qkv<<<dim3(576), blk, 0, stream>>>(xtq, xtc, wqb, wkb, wvb,
                                            qtb, ktb, vcb);

    attn<<<dim3(768), blk, 0, stream>>>(qtb, ktb, vcb, omid, rws);

    tail_k<<<dim3(1728), blk, 0, stream>>>(wob, omid, bo, out,
                                           qtb, ktb, rws, attn_map);
}